// Round 4
// baseline (803.781 us; speedup 1.0000x reference)
//
#include <hip/hip_runtime.h>
#include <hip/hip_bf16.h>

// Problem constants (fixed shapes from setup_inputs)
#define M_DIM 8192   // B*S = 4*2048
#define N_DIM 4096   // D_OUT
#define DK    4096   // D_IN
#define R_DIM 64
#define KX    4160   // DK + R_DIM (K-extended GEMM); 4160 = 65*64
#define SPLITK 8
#define KCHUNK (DK / SPLITK)  // 512
// SCALE = ALPHA/K = 16/16 = 1.0

typedef __bf16 bf16x8 __attribute__((ext_vector_type(8)));
typedef float f32x4 __attribute__((ext_vector_type(4)));
typedef unsigned short ushort8 __attribute__((ext_vector_type(8)));

__device__ __forceinline__ unsigned short f2bf_rne(float f) {
  union { float f; unsigned int u; } v; v.f = f;
  unsigned int u = v.u;
  return (unsigned short)((u + 0x7fffu + ((u >> 16) & 1u)) >> 16);
}

__device__ __forceinline__ ushort8 cvt8(float4 f0, float4 f1) {
  ushort8 o;
  o[0] = f2bf_rne(f0.x); o[1] = f2bf_rne(f0.y);
  o[2] = f2bf_rne(f0.z); o[3] = f2bf_rne(f0.w);
  o[4] = f2bf_rne(f1.x); o[5] = f2bf_rne(f1.y);
  o[6] = f2bf_rne(f1.z); o[7] = f2bf_rne(f1.w);
  return o;
}

// async global->LDS, 16B per lane; lds dest is wave-uniform base + lane*16
__device__ __forceinline__ void load16_to_lds(const void* g, void* l) {
  __builtin_amdgcn_global_load_lds(
      (__attribute__((address_space(1))) void*)(unsigned long long)(const char*)g,
      (__attribute__((address_space(3))) void*)(unsigned int)(unsigned long long)(char*)l,
      16, 0, 0);
}

// Chunk-linear LDS layout: chunk = 1KB = 16 rows x 32 k (bf16).
// Slot L (16B) holds (row = L&15, k-octet = L>>4)  == the MFMA fragment mapping,
// so fragment ds_read_b128 at chunkbase + lane*16 is bank-conflict-free (2/bank),
// and global_load_lds's implicit "+lane*16" dest matches when the SOURCE address
// is computed per-lane as (row=lane&15, k-seg=lane>>4).

// ---------------- fused: x fp32 -> bf16 -> (xext write + z split-K MFMA) ----------------
// grid (M/64, SPLITK) = (128, 8) = 1024 blocks (4/CU); block 256.
// Per block: 64 x-rows x 512-K chunk; LDS chunks 0-3 = x rows, 4-7 = A rows.
__global__ __launch_bounds__(256) void xz_kernel(
    const float* __restrict__ x, const float* __restrict__ A,
    unsigned short* __restrict__ xext, float* __restrict__ zpart) {
  __shared__ unsigned short L[8 * 512];  // 8 KB

  const int tid = threadIdx.x;
  const int wave = tid >> 6;
  const int lane = tid & 63;
  const int rowBase = blockIdx.x * 64;
  const int kc = blockIdx.y;
  const int kBase = kc * KCHUNK;

  // staging role: thread -> chunk c (0..7), within-chunk worker i (0..31)
  const int c = tid >> 5;
  const int i = tid & 31;
  const int b = i >> 4;    // which 16-float column half
  const int row = i & 15;

  const float* src = (c < 4)
      ? (x + (size_t)(rowBase + c * 16 + row) * DK + kBase + b * 16)
      : (A + (size_t)((c - 4) * 16 + row) * DK + kBase + b * 16);
  unsigned short* xdst =
      xext + (size_t)(rowBase + (c & 3) * 16 + row) * KX + kBase + b * 16;
  unsigned short* w0 = &L[c * 512 + ((2 * b) * 16 + row) * 8];
  unsigned short* w1 = &L[c * 512 + ((2 * b + 1) * 16 + row) * 8];

  const float4* s4 = (const float4*)src;
  float4 v0 = s4[0], v1 = s4[1], v2 = s4[2], v3 = s4[3];

  f32x4 acc[4] = {};

  for (int k0 = 0; k0 < KCHUNK; k0 += 32) {
    ushort8 b0 = cvt8(v0, v1);
    ushort8 b1 = cvt8(v2, v3);
    __syncthreads();  // prior iter's ds_reads done before overwrite
    *(ushort8*)w0 = b0;
    *(ushort8*)w1 = b1;
    if (k0 + 32 < KCHUNK) {  // prefetch next iter (stays in flight across barrier)
      const float4* n4 = (const float4*)(src + k0 + 32);
      v0 = n4[0]; v1 = n4[1]; v2 = n4[2]; v3 = n4[3];
    }
    __syncthreads();  // staging visible
    if (c < 4) {      // persist bf16 x into xext
      *(ushort8*)(xdst + k0) = b0;
      *(ushort8*)(xdst + k0 + 8) = b1;
    }
    // wave w computes x-rows [rowBase+16w .. +16) x all 64 A-rows
    bf16x8 af = *(const bf16x8*)&L[wave * 512 + lane * 8];
    bf16x8 bf[4];
#pragma unroll
    for (int j = 0; j < 4; ++j)
      bf[j] = *(const bf16x8*)&L[(4 + j) * 512 + lane * 8];
#pragma unroll
    for (int j = 0; j < 4; ++j)
      acc[j] = __builtin_amdgcn_mfma_f32_16x16x32_bf16(af, bf[j], acc[j], 0, 0, 0);
  }

  const int fr = lane & 15, quad = lane >> 4;
  const int row0 = rowBase + wave * 16 + quad * 4;
#pragma unroll
  for (int j = 0; j < 4; ++j) {
    int col = j * 16 + fr;
#pragma unroll
    for (int r = 0; r < 4; ++r)
      zpart[((size_t)kc * M_DIM + row0 + r) * R_DIM + col] = acc[j][r];
  }
}

// ---------------- W & B fp32 -> bf16 into wext [N][4160] ----------------
__global__ __launch_bounds__(256) void wcvt_kernel(
    const float* __restrict__ W, const float* __restrict__ Bm,
    unsigned short* __restrict__ wext) {
  int idx = blockIdx.x * 256 + threadIdx.x;  // 8-element chunk id; total 4096*520
  int row = idx / 520;
  int c8 = idx - row * 520;
  const float* src = (c8 < 512) ? (W + (size_t)row * DK + c8 * 8)
                                : (Bm + (size_t)row * R_DIM + (c8 - 512) * 8);
  float4 f0 = *(const float4*)src;
  float4 f1 = *(const float4*)(src + 4);
  *(ushort8*)(wext + (size_t)row * KX + c8 * 8) = cvt8(f0, f1);
}

// ---------------- reduce partials, soft top-k mask, write bf16 into x_ext tail ----------------
__global__ __launch_bounds__(256) void mask_kernel(
    const float* __restrict__ zpart, unsigned short* __restrict__ xext) {
  const int wave = threadIdx.x >> 6;
  const int lane = threadIdx.x & 63;
  const int row = blockIdx.x * 4 + wave;

  float v = 0.f;
#pragma unroll
  for (int k = 0; k < SPLITK; ++k)
    v += zpart[((size_t)k * M_DIM + row) * R_DIM + lane];

  float a = fabsf(v);
  // rank-select the 16th-largest |z| (tie-safe): cnt_gt <= 15 < cnt_ge
  int cnt_gt = 0, cnt_ge = 0;
#pragma unroll
  for (int i = 0; i < 64; ++i) {
    float o = __shfl(a, i);
    cnt_gt += (o > a) ? 1 : 0;
    cnt_ge += (o >= a) ? 1 : 0;
  }
  float cand = (cnt_gt <= 15 && cnt_ge > 15) ? a : -1.f;
#pragma unroll
  for (int off = 32; off; off >>= 1) cand = fmaxf(cand, __shfl_xor(cand, off));
  float thr = cand;
  float mask = 1.f / (1.f + __expf(-(a - thr) * 10.0f));  // TEMP=0.1
  xext[(size_t)row * KX + DK + lane] = f2bf_rne(v * mask);  // SCALE == 1.0
}

// ---------------- main GEMM: out[m][n] = sum_k xext[m][k]*wext[n][k] + bias[n] ----------------
// 128x128 tile, BK=64 (65 iters, halved barrier drains), 4 waves 2x2, 4x4 MFMA/wave.
// Chunk-linear LDS (16 chunks/tile, ci = kk*8 + rowgroup): zero bank conflicts.
__global__ __launch_bounds__(256, 3) void gemm_kernel(
    const unsigned short* __restrict__ Ag,   // [M_DIM][KX] bf16
    const unsigned short* __restrict__ Bg,   // [N_DIM][KX] bf16
    const float* __restrict__ bias,
    float* __restrict__ out) {
  __shared__ unsigned short AsL[16 * 512];  // 16 KB
  __shared__ unsigned short BsL[16 * 512];  // 16 KB

  const int tid = threadIdx.x;
  const int wave = tid >> 6;
  const int lane = tid & 63;
  const int rowBase = blockIdx.y * 128;
  const int colBase = blockIdx.x * 128;
  const int wm16 = (wave & 1) * 4;   // A row-group base (units of 16 rows)
  const int wn16 = (wave >> 1) * 4;

  const int frow = lane & 15;
  const int fseg = lane >> 4;        // k-octet within 32-k chunk

  // staging: wave handles chunks ci = wave + 4t (t=0..3) for both A and B
  const unsigned short* aP[4];
  const unsigned short* bP[4];
  unsigned short* aL[4];
  unsigned short* bL[4];
#pragma unroll
  for (int t = 0; t < 4; ++t) {
    int ci = wave + t * 4;
    int kk = ci >> 3, rg = ci & 7;
    aP[t] = Ag + (size_t)(rowBase + rg * 16 + frow) * KX + kk * 32 + fseg * 8;
    bP[t] = Bg + (size_t)(colBase + rg * 16 + frow) * KX + kk * 32 + fseg * 8;
    aL[t] = &AsL[ci * 512];
    bL[t] = &BsL[ci * 512];
  }

  f32x4 acc[4][4] = {};

  for (int k0 = 0; k0 < KX; k0 += 64) {
    __syncthreads();
#pragma unroll
    for (int t = 0; t < 4; ++t) {
      load16_to_lds(aP[t] + k0, aL[t]);
      load16_to_lds(bP[t] + k0, bL[t]);
    }
    __syncthreads();

#pragma unroll
    for (int kk = 0; kk < 2; ++kk) {
      bf16x8 af[4], bf[4];
#pragma unroll
      for (int i = 0; i < 4; ++i)
        af[i] = *(const bf16x8*)&AsL[(kk * 8 + wm16 + i) * 512 + lane * 8];
#pragma unroll
      for (int j = 0; j < 4; ++j)
        bf[j] = *(const bf16x8*)&BsL[(kk * 8 + wn16 + j) * 512 + lane * 8];
#pragma unroll
      for (int i = 0; i < 4; ++i)
#pragma unroll
        for (int j = 0; j < 4; ++j)
          acc[i][j] = __builtin_amdgcn_mfma_f32_16x16x32_bf16(af[i], bf[j],
                                                              acc[i][j], 0, 0, 0);
    }
  }

  // epilogue: C/D layout col=lane&15, row=(lane>>4)*4+reg
  const int wm = wm16 * 16, wn = wn16 * 16;
  const int quad = lane >> 4;
#pragma unroll
  for (int j = 0; j < 4; ++j) {
    int col = colBase + wn + j * 16 + frow;
    float bv = bias[col];
#pragma unroll
    for (int i = 0; i < 4; ++i) {
      int row0 = rowBase + wm + i * 16 + quad * 4;
#pragma unroll
      for (int r = 0; r < 4; ++r)
        out[(size_t)(row0 + r) * N_DIM + col] = acc[i][j][r] + bv;
    }
  }
}

extern "C" void kernel_launch(void* const* d_in, const int* in_sizes, int n_in,
                              void* d_out, int out_size, void* d_ws, size_t ws_size,
                              hipStream_t stream) {
  const float* x    = (const float*)d_in[0];  // (4,2048,4096)
  const float* A    = (const float*)d_in[1];  // (64,4096)
  const float* B    = (const float*)d_in[2];  // (4096,64)
  const float* W    = (const float*)d_in[3];  // (4096,4096)
  const float* bias = (const float*)d_in[4];  // (4096,)
  float* out = (float*)d_out;

  // workspace layout (all 16B-aligned):
  //   xext  [8192][4160] bf16  = 68.16 MB
  //   wext  [4096][4160] bf16  = 34.08 MB
  //   zpart [8][8192][64] fp32 = 16.78 MB   (total 119.0 MB)
  unsigned short* xext = (unsigned short*)d_ws;
  unsigned short* wext = xext + (size_t)M_DIM * KX;
  float*          zpart = (float*)(wext + (size_t)N_DIM * KX);

  dim3 zgrid(M_DIM / 64, SPLITK);  // 128 x 8 = 1024 blocks
  xz_kernel<<<zgrid, 256, 0, stream>>>(x, A, xext, zpart);
  wcvt_kernel<<<(N_DIM * (KX / 8) + 255) / 256, 256, 0, stream>>>(W, B, wext);
  mask_kernel<<<M_DIM / 4, 256, 0, stream>>>(zpart, xext);

  dim3 grid(N_DIM / 128, M_DIM / 128);  // 32 x 64
  gemm_kernel<<<grid, 256, 0, stream>>>(xext, wext, bias, out);
}